// Round 4
// baseline (340.685 us; speedup 1.0000x reference)
//
#include <hip/hip_runtime.h>

// Shapes (fixed by the reference): B=4096, V=64, DI=DO=128. All I/O is f32
// (verified R2: k_mix WRITE_SIZE == 4096*64*128*4 B).
#define BN 4096
#define VN 64
#define DI 128
#define DO 128

typedef __attribute__((ext_vector_type(8))) short short8;
typedef __attribute__((ext_vector_type(4))) float f32x4;

__device__ __forceinline__ float bf2f(unsigned short s) {
    return __uint_as_float(((unsigned)s) << 16);
}
__device__ __forceinline__ unsigned short f2bf(float f) {   // RNE
    unsigned u = __float_as_uint(f);
    u += 0x7FFF + ((u >> 16) & 1);
    return (unsigned short)(u >> 16);
}
// pack bf16(lo)|bf16(hi)<<16 via byte-perm (truncation) — 1 VALU op / 2 elems
__device__ __forceinline__ unsigned pack_bf16_trunc(float lo, float hi) {
    return __builtin_amdgcn_perm(__float_as_uint(hi), __float_as_uint(lo), 0x07060302u);
}

// ---------------------------------------------------------------------------
// Kernel 0: prep.
// Blocks 0..511 (v = blk>>3, q = blk&7): transpose W[v] (DIxDO f32) ->
//   Wt[v] (DOxDI bf16), reads coalesced along o.
// Block 512: adj f32 -> adjbf (bf16 row-major [u][v]).
// No zeroing needed: all scratch is fully overwritten every launch.
// ---------------------------------------------------------------------------
__global__ __launch_bounds__(256) void k_prep(const float* __restrict__ W,
                                              const float* __restrict__ adj,
                                              unsigned short* __restrict__ Wt,
                                              unsigned short* __restrict__ adjbf) {
    const int t = threadIdx.x, blk = blockIdx.x;
    if (blk < 512) {
        const int v = blk >> 3, q = blk & 7;
        const float* Wv = W + (size_t)v * DI * DO;
        unsigned short* Wtv = Wt + (size_t)v * DI * DO;
        const int o = t & 127;
        const int i0 = q * 16 + (t >> 7) * 8;
        short8 s0;
#pragma unroll
        for (int j = 0; j < 8; ++j)
            s0[j] = (short)f2bf(Wv[(size_t)(i0 + j) * DO + o]);
        *(short8*)(Wtv + o * DI + i0) = s0;
    } else {
        short8 s0, s1;
#pragma unroll
        for (int j = 0; j < 8; ++j) s0[j] = (short)f2bf(adj[t * 16 + j]);
#pragma unroll
        for (int j = 0; j < 8; ++j) s1[j] = (short)f2bf(adj[t * 16 + 8 + j]);
        *(short8*)(adjbf + t * 16) = s0;
        *(short8*)(adjbf + t * 16 + 8) = s1;
    }
}

// ---------------------------------------------------------------------------
// Kernel 1: grouped GEMM h[b,v,o] = feat[b,v,:] @ W[v,:,:] + bias[v,:]
// grid (32 b-tiles, 64 v), block 256 (2x2 waves), 128x128 tile, bf16 MFMA.
// All B (Wt, L2-hot) loaded up-front; A (feat f32) software-pipelined one
// k-step ahead and packed to bf16 via v_perm. BN partials -> race-free
// per-(v,bt,wm) stores (NO atomics — R3's 110us stall was atomic drain).
// ---------------------------------------------------------------------------
__global__ __launch_bounds__(256) void k_gemm1(const float* __restrict__ feat,
                                               const unsigned short* __restrict__ Wt,
                                               const float* __restrict__ bias,
                                               unsigned short* __restrict__ h,
                                               float* __restrict__ psA,
                                               float* __restrict__ psB) {
    const int bt = blockIdx.x;
    const int v = blockIdx.y;
    const int tid = threadIdx.x;
    const int w = tid >> 6, lane = tid & 63;
    const int wm = w >> 1, wn = w & 1;
    const int quad = lane >> 4, l16 = lane & 15;

    size_t aidx[4];
#pragma unroll
    for (int rt = 0; rt < 4; ++rt)
        aidx[rt] = (size_t)(bt * 128 + wm * 64 + rt * 16 + l16) * (VN * DI)
                 + v * DI + quad * 8;

    // all B fragments up-front: 4 k-steps x 4 nt x 16 B (L2-hot, 32 KB/v)
    short8 bb[4][4];
#pragma unroll
    for (int ks = 0; ks < 4; ++ks)
#pragma unroll
        for (int nt = 0; nt < 4; ++nt)
            bb[ks][nt] = *(const short8*)(Wt + (size_t)v * (DI * DO)
                                          + (size_t)(wn * 64 + nt * 16 + l16) * DI
                                          + quad * 8 + ks * 32);

    f32x4 acc[4][4];
#pragma unroll
    for (int rt = 0; rt < 4; ++rt)
#pragma unroll
        for (int nt = 0; nt < 4; ++nt) acc[rt][nt] = (f32x4){0.f, 0.f, 0.f, 0.f};

#define LOADA(dst, k0)                                                        \
    {                                                                         \
        _Pragma("unroll") for (int rt = 0; rt < 4; ++rt) {                    \
            f32x4 f0 = *(const f32x4*)(feat + aidx[rt] + (k0));               \
            f32x4 f1 = *(const f32x4*)(feat + aidx[rt] + (k0) + 4);          \
            union { short8 s; unsigned u[4]; } pk;                            \
            pk.u[0] = pack_bf16_trunc(f0[0], f0[1]);                          \
            pk.u[1] = pack_bf16_trunc(f0[2], f0[3]);                          \
            pk.u[2] = pack_bf16_trunc(f1[0], f1[1]);                          \
            pk.u[3] = pack_bf16_trunc(f1[2], f1[3]);                          \
            dst[rt] = pk.s;                                                   \
        }                                                                     \
    }

    short8 aCur[4], aNxt[4];
    LOADA(aCur, 0)
#pragma unroll
    for (int ks = 0; ks < 4; ++ks) {
        if (ks < 3) LOADA(aNxt, (ks + 1) * 32)
#pragma unroll
        for (int rt = 0; rt < 4; ++rt)
#pragma unroll
            for (int nt = 0; nt < 4; ++nt)
                acc[rt][nt] = __builtin_amdgcn_mfma_f32_16x16x32_bf16(
                    aCur[rt], bb[ks][nt], acc[rt][nt], 0, 0, 0);
#pragma unroll
        for (int rt = 0; rt < 4; ++rt) aCur[rt] = aNxt[rt];
    }
#undef LOADA

    // epilogue: +bias, per-(wave,col) partial sums over 64 rows, store h bf16
#pragma unroll
    for (int nt = 0; nt < 4; ++nt) {
        const int col = wn * 64 + nt * 16 + l16;
        const float bv = bias[v * DO + col];
        float s = 0.f, sq = 0.f;
#pragma unroll
        for (int rt = 0; rt < 4; ++rt)
#pragma unroll
            for (int e = 0; e < 4; ++e) {
                float x = acc[rt][nt][e] + bv;
                acc[rt][nt][e] = x;
                s += x;
                sq += x * x;
            }
        s += __shfl_down(s, 32);  s += __shfl_down(s, 16);
        sq += __shfl_down(sq, 32); sq += __shfl_down(sq, 16);
        if (lane < 16) {
            const size_t pi = ((size_t)(v * 32 + bt) * 2 + wm) * 128 + col;
            psA[pi] = s;
            psB[pi] = sq;
        }
#pragma unroll
        for (int rt = 0; rt < 4; ++rt)
#pragma unroll
            for (int e = 0; e < 4; ++e) {
                int brow = bt * 128 + wm * 64 + rt * 16 + quad * 4 + e;
                h[(size_t)brow * (VN * DO) + v * DO + col] = f2bf(acc[rt][nt][e]);
            }
    }
}

// ---------------------------------------------------------------------------
// Kernel 2a: reduce partials -> scale[v,o], shift[v,o]. 64 blocks (v).
// ---------------------------------------------------------------------------
__global__ __launch_bounds__(128) void k_reduce(const float* __restrict__ psA,
                                                const float* __restrict__ psB,
                                                const float* __restrict__ gamma,
                                                const float* __restrict__ beta,
                                                float* __restrict__ scale,
                                                float* __restrict__ shift) {
    const int o = threadIdx.x;
    const int v = blockIdx.x;
    float s = 0.f, sq = 0.f;
#pragma unroll
    for (int p = 0; p < 64; ++p) {
        const size_t pi = ((size_t)v * 64 + p) * 128 + o;
        s += psA[pi];
        sq += psB[pi];
    }
    const float invB = 1.0f / (float)BN;
    const float mu = s * invB;
    const float var = sq * invB - mu * mu;
    const float sc = gamma[v * DO + o] * rsqrtf(var + 1e-5f);
    scale[v * DO + o] = sc;
    shift[v * DO + o] = beta[v * DO + o] - mu * sc;
}

// ---------------------------------------------------------------------------
// Kernel 2b: C0[u,o] = sum_v adj[u,v] * shift[v,o]. 64 blocks (u).
// ---------------------------------------------------------------------------
__global__ __launch_bounds__(128) void k_c0(const float* __restrict__ adj,
                                            const float* __restrict__ shift,
                                            float* __restrict__ C0) {
    const int o = threadIdx.x;
    const int u = blockIdx.x;
    float c0 = 0.f;
#pragma unroll
    for (int v = 0; v < VN; ++v)
        c0 += adj[u * VN + v] * shift[v * DO + o];
    C0[u * DO + o] = c0;
}

// ---------------------------------------------------------------------------
// Kernel 3 (MFMA mix): out[b,u,o] = relu( sum_v adj[u,v]*(h[b,v,o]*scale[v,o])
//                                         + C0[u,o] )
// Block = 2 batch elems, 4 waves; wave (bl, nh) does M=64 x N=64 (o-half).
// h*scale staged to LDS transposed hsT[o][v] (pad 72). adj A-frags from
// global bf16 (8 KB, L2-hot).
// ---------------------------------------------------------------------------
__global__ __launch_bounds__(256) void k_mix(const unsigned short* __restrict__ h,
                                             const float* __restrict__ scale,
                                             const unsigned short* __restrict__ adjbf,
                                             const float* __restrict__ C0,
                                             float* __restrict__ out) {
    __shared__ unsigned short hsT[2][DO][72];   // 36,864 B
    const int t = threadIdx.x;
    const int b0 = blockIdx.x * 2;

    const int sv = t & 63;
#pragma unroll
    for (int c = 0; c < 8; ++c) {
        const int bl = c >> 2;
        const int o0 = ((t >> 6) << 3) + (c & 3) * 32;
        short8 hv = *(const short8*)(h + ((size_t)(b0 + bl) * VN + sv) * DO + o0);
        f32x4 s0 = *(const f32x4*)(scale + sv * DO + o0);
        f32x4 s1 = *(const f32x4*)(scale + sv * DO + o0 + 4);
#pragma unroll
        for (int j = 0; j < 4; ++j)
            hsT[bl][o0 + j][sv] = f2bf(bf2f((unsigned short)hv[j]) * s0[j]);
#pragma unroll
        for (int j = 0; j < 4; ++j)
            hsT[bl][o0 + 4 + j][sv] = f2bf(bf2f((unsigned short)hv[4 + j]) * s1[j]);
    }
    __syncthreads();

    const int w = t >> 6, lane = t & 63;
    const int bl = w >> 1, nh = w & 1;
    const int quad = lane >> 4, l16 = lane & 15;
    const int b = b0 + bl;

    short8 af[4][2];
#pragma unroll
    for (int mt = 0; mt < 4; ++mt)
#pragma unroll
        for (int ks = 0; ks < 2; ++ks)
            af[mt][ks] = *(const short8*)(adjbf + (mt * 16 + l16) * VN
                                          + ks * 32 + quad * 8);

    f32x4 acc[4][4];
#pragma unroll
    for (int mt = 0; mt < 4; ++mt)
#pragma unroll
        for (int nt = 0; nt < 4; ++nt) acc[mt][nt] = (f32x4){0.f, 0.f, 0.f, 0.f};

#pragma unroll
    for (int nt = 0; nt < 4; ++nt) {
        const unsigned short* bp = &hsT[bl][nh * 64 + nt * 16 + l16][quad * 8];
        short8 bf0 = *(const short8*)(bp);
        short8 bf1 = *(const short8*)(bp + 32);
#pragma unroll
        for (int mt = 0; mt < 4; ++mt) {
            acc[mt][nt] = __builtin_amdgcn_mfma_f32_16x16x32_bf16(
                af[mt][0], bf0, acc[mt][nt], 0, 0, 0);
            acc[mt][nt] = __builtin_amdgcn_mfma_f32_16x16x32_bf16(
                af[mt][1], bf1, acc[mt][nt], 0, 0, 0);
        }
    }

#pragma unroll
    for (int mt = 0; mt < 4; ++mt)
#pragma unroll
        for (int nt = 0; nt < 4; ++nt) {
            const int o = nh * 64 + nt * 16 + l16;
#pragma unroll
            for (int e = 0; e < 4; ++e) {
                const int u = mt * 16 + quad * 4 + e;
                out[((size_t)b * VN + u) * DO + o] =
                    fmaxf(acc[mt][nt][e] + C0[u * DO + o], 0.0f);
            }
        }
}

// ---------------------------------------------------------------------------
extern "C" void kernel_launch(void* const* d_in, const int* in_sizes, int n_in,
                              void* d_out, int out_size, void* d_ws, size_t ws_size,
                              hipStream_t stream) {
    const float* feat  = (const float*)d_in[0];
    const float* adj   = (const float*)d_in[1];
    const float* W     = (const float*)d_in[2];
    const float* bias  = (const float*)d_in[3];
    const float* gamma = (const float*)d_in[4];
    const float* beta  = (const float*)d_in[5];
    float* out = (float*)d_out;

    char* ws = (char*)d_ws;
    unsigned short* h     = (unsigned short*)ws;                 // 67,108,864 B
    unsigned short* Wt    = (unsigned short*)(ws + 67108864ull); //  2,097,152 B
    unsigned short* adjbf = (unsigned short*)(ws + 69206016ull); //      8,192 B
    float* psA   = (float*)(ws + 69214208ull);                   //  2 MiB
    float* psB   = psA + 524288;                                 //  2 MiB
    float* scale = psB + 524288;                                 // 32 KiB
    float* shift = scale + 8192;                                 // 32 KiB
    float* C0    = shift + 8192;                                 // 32 KiB

    k_prep<<<dim3(513), dim3(256), 0, stream>>>(W, adj, Wt, adjbf);
    k_gemm1<<<dim3(32, 64), dim3(256), 0, stream>>>(feat, Wt, bias, h, psA, psB);
    k_reduce<<<dim3(64), dim3(128), 0, stream>>>(psA, psB, gamma, beta, scale, shift);
    k_c0<<<dim3(64), dim3(128), 0, stream>>>(adj, shift, C0);
    k_mix<<<dim3(2048), dim3(256), 0, stream>>>(h, scale, adjbf, C0, out);
}

// Round 5
// 298.894 us; speedup vs baseline: 1.1398x; 1.1398x over previous
//
#include <hip/hip_runtime.h>

// Shapes (fixed by the reference): B=4096, V=64, DI=DO=128. All I/O f32.
#define BN 4096
#define VN 64
#define DI 128
#define DO 128

typedef __attribute__((ext_vector_type(8))) short short8;
typedef __attribute__((ext_vector_type(4))) float f32x4;

__device__ __forceinline__ float bf2f(unsigned short s) {
    return __uint_as_float(((unsigned)s) << 16);
}
__device__ __forceinline__ unsigned short f2bf(float f) {   // RNE
    unsigned u = __float_as_uint(f);
    u += 0x7FFF + ((u >> 16) & 1);
    return (unsigned short)(u >> 16);
}
// trunc pack (A-inputs only; h uses RNE)
__device__ __forceinline__ unsigned pack_bf16_trunc(float lo, float hi) {
    return __builtin_amdgcn_perm(__float_as_uint(hi), __float_as_uint(lo), 0x07060302u);
}
__device__ __forceinline__ unsigned pack_bf16_rne(float lo, float hi) {
    return (unsigned)f2bf(lo) | ((unsigned)f2bf(hi) << 16);
}

// h is stored in MFMA C-fragment layout (bf16 units):
//   Hoff(bt,v,w,nt,rt,lane,e) = (((((bt*64+v)*4+w)*4+nt)*4+rt)*64 + lane)*4 + e
// where (w=wm*2+wn, nt, rt) are k_gemm1's tile coords, lane=quad*16+l16,
// e = row-within-quad. Row b = bt*128+wm*64+rt*16+quad*4+e, col o = wn*64+nt*16+l16.
// Each block writes one contiguous 32 KB slab; each wave store = 512 B.

// ---------------------------------------------------------------------------
// Kernel 0: prep. Blocks 0..511: transpose W[v] f32 -> Wt[v] (DOxDI bf16).
// Block 512: adj f32 -> adjbf bf16.
// ---------------------------------------------------------------------------
__global__ __launch_bounds__(256) void k_prep(const float* __restrict__ W,
                                              const float* __restrict__ adj,
                                              unsigned short* __restrict__ Wt,
                                              unsigned short* __restrict__ adjbf) {
    const int t = threadIdx.x, blk = blockIdx.x;
    if (blk < 512) {
        const int v = blk >> 3, q = blk & 7;
        const float* Wv = W + (size_t)v * DI * DO;
        unsigned short* Wtv = Wt + (size_t)v * DI * DO;
        const int o = t & 127;
        const int i0 = q * 16 + (t >> 7) * 8;
        short8 s0;
#pragma unroll
        for (int j = 0; j < 8; ++j)
            s0[j] = (short)f2bf(Wv[(size_t)(i0 + j) * DO + o]);
        *(short8*)(Wtv + o * DI + i0) = s0;
    } else {
        short8 s0, s1;
#pragma unroll
        for (int j = 0; j < 8; ++j) s0[j] = (short)f2bf(adj[t * 16 + j]);
#pragma unroll
        for (int j = 0; j < 8; ++j) s1[j] = (short)f2bf(adj[t * 16 + 8 + j]);
        *(short8*)(adjbf + t * 16) = s0;
        *(short8*)(adjbf + t * 16 + 8) = s1;
    }
}

// ---------------------------------------------------------------------------
// Kernel 1: grouped GEMM h = feat @ W[v] + b[v], 128x128 tile, bf16 MFMA.
// grid (64 v, 32 bt): concurrent blocks span all v for one bt -> contiguous
// combined DRAM footprint (R4 was 512B-granular scatter at 1.75 TB/s).
// h stored in fragment layout (contiguous 512B wave stores).
// ---------------------------------------------------------------------------
__global__ __launch_bounds__(256) void k_gemm1(const float* __restrict__ feat,
                                               const unsigned short* __restrict__ Wt,
                                               const float* __restrict__ bias,
                                               unsigned short* __restrict__ h,
                                               float* __restrict__ psA,
                                               float* __restrict__ psB) {
    const int v = blockIdx.x;
    const int bt = blockIdx.y;
    const int tid = threadIdx.x;
    const int w = tid >> 6, lane = tid & 63;
    const int wm = w >> 1, wn = w & 1;
    const int quad = lane >> 4, l16 = lane & 15;

    size_t aidx[4];
#pragma unroll
    for (int rt = 0; rt < 4; ++rt)
        aidx[rt] = (size_t)(bt * 128 + wm * 64 + rt * 16 + l16) * (VN * DI)
                 + v * DI + quad * 8;

    // all B fragments up-front (Wt[v] is XCD-L2-hot: XCD = v%8 for all bt)
    short8 bb[4][4];
#pragma unroll
    for (int ks = 0; ks < 4; ++ks)
#pragma unroll
        for (int nt = 0; nt < 4; ++nt)
            bb[ks][nt] = *(const short8*)(Wt + (size_t)v * (DI * DO)
                                          + (size_t)(wn * 64 + nt * 16 + l16) * DI
                                          + quad * 8 + ks * 32);

    f32x4 acc[4][4];
#pragma unroll
    for (int rt = 0; rt < 4; ++rt)
#pragma unroll
        for (int nt = 0; nt < 4; ++nt) acc[rt][nt] = (f32x4){0.f, 0.f, 0.f, 0.f};

#define LOADA(dst, k0)                                                        \
    {                                                                         \
        _Pragma("unroll") for (int rt = 0; rt < 4; ++rt) {                    \
            f32x4 f0 = *(const f32x4*)(feat + aidx[rt] + (k0));               \
            f32x4 f1 = *(const f32x4*)(feat + aidx[rt] + (k0) + 4);          \
            union { short8 s; unsigned u[4]; } pk;                            \
            pk.u[0] = pack_bf16_trunc(f0[0], f0[1]);                          \
            pk.u[1] = pack_bf16_trunc(f0[2], f0[3]);                          \
            pk.u[2] = pack_bf16_trunc(f1[0], f1[1]);                          \
            pk.u[3] = pack_bf16_trunc(f1[2], f1[3]);                          \
            dst[rt] = pk.s;                                                   \
        }                                                                     \
    }

    short8 aCur[4], aNxt[4];
    LOADA(aCur, 0)
#pragma unroll
    for (int ks = 0; ks < 4; ++ks) {
        if (ks < 3) LOADA(aNxt, (ks + 1) * 32)
#pragma unroll
        for (int rt = 0; rt < 4; ++rt)
#pragma unroll
            for (int nt = 0; nt < 4; ++nt)
                acc[rt][nt] = __builtin_amdgcn_mfma_f32_16x16x32_bf16(
                    aCur[rt], bb[ks][nt], acc[rt][nt], 0, 0, 0);
#pragma unroll
        for (int rt = 0; rt < 4; ++rt) aCur[rt] = aNxt[rt];
    }
#undef LOADA

    // epilogue: +bias, BN partials (race-free), fragment-layout h stores
    unsigned short* hblk = h + ((size_t)(bt * 64 + v) * 4 + w) * 4096;
#pragma unroll
    for (int nt = 0; nt < 4; ++nt) {
        const int col = wn * 64 + nt * 16 + l16;
        const float bv = bias[v * DO + col];
        float s = 0.f, sq = 0.f;
#pragma unroll
        for (int rt = 0; rt < 4; ++rt)
#pragma unroll
            for (int e = 0; e < 4; ++e) {
                float x = acc[rt][nt][e] + bv;
                acc[rt][nt][e] = x;
                s += x;
                sq += x * x;
            }
        s += __shfl_down(s, 32);  s += __shfl_down(s, 16);
        sq += __shfl_down(sq, 32); sq += __shfl_down(sq, 16);
        if (lane < 16) {
            const size_t pi = ((size_t)(v * 32 + bt) * 2 + wm) * 128 + col;
            psA[pi] = s;
            psB[pi] = sq;
        }
#pragma unroll
        for (int rt = 0; rt < 4; ++rt) {
            uint2 pk;
            pk.x = pack_bf16_rne(acc[rt][nt][0], acc[rt][nt][1]);
            pk.y = pack_bf16_rne(acc[rt][nt][2], acc[rt][nt][3]);
            *(uint2*)(hblk + (size_t)((nt * 4 + rt) * 64 + lane) * 4) = pk;
        }
    }
}

// ---------------------------------------------------------------------------
// Kernel 2a: reduce partials -> scale, shift. 64 blocks (v).
// ---------------------------------------------------------------------------
__global__ __launch_bounds__(128) void k_reduce(const float* __restrict__ psA,
                                                const float* __restrict__ psB,
                                                const float* __restrict__ gamma,
                                                const float* __restrict__ beta,
                                                float* __restrict__ scale,
                                                float* __restrict__ shift) {
    const int o = threadIdx.x;
    const int v = blockIdx.x;
    float s = 0.f, sq = 0.f;
#pragma unroll
    for (int p = 0; p < 64; ++p) {
        const size_t pi = ((size_t)v * 64 + p) * 128 + o;
        s += psA[pi];
        sq += psB[pi];
    }
    const float invB = 1.0f / (float)BN;
    const float mu = s * invB;
    const float var = sq * invB - mu * mu;
    const float sc = gamma[v * DO + o] * rsqrtf(var + 1e-5f);
    scale[v * DO + o] = sc;
    shift[v * DO + o] = beta[v * DO + o] - mu * sc;
}

// ---------------------------------------------------------------------------
// Kernel 2b: C0[u,o] = sum_v adj[u,v] * shift[v,o]. 64 blocks (u).
// ---------------------------------------------------------------------------
__global__ __launch_bounds__(128) void k_c0(const float* __restrict__ adj,
                                            const float* __restrict__ shift,
                                            float* __restrict__ C0) {
    const int o = threadIdx.x;
    const int u = blockIdx.x;
    float c0 = 0.f;
#pragma unroll
    for (int v = 0; v < VN; ++v)
        c0 += adj[u * VN + v] * shift[v * DO + o];
    C0[u * DO + o] = c0;
}

// ---------------------------------------------------------------------------
// Kernel 3 (MFMA mix): out[b,u,o] = relu( sum_v adj[u,v]*(h[b,v,o]*scale[v,o])
//                                         + C0[u,o] )
// Block = 4 batch elems (one e-quad of the fragment layout), 512 threads.
// Stage h*scale from fragment layout (128 B-chunk coalesced reads) into
// hsT[e][o][v] (pad 72). 8 waves: (bl=w>>1 batch, nh=w&1 o-half), M=64xN=64.
// ---------------------------------------------------------------------------
__global__ __launch_bounds__(512, 4) void k_mix(const unsigned short* __restrict__ h,
                                                const float* __restrict__ scale,
                                                const unsigned short* __restrict__ adjbf,
                                                const float* __restrict__ C0,
                                                float* __restrict__ out) {
    __shared__ unsigned short hsT[4][DO][72];   // 73,728 B
    const int t = threadIdx.x;
    const int b0 = blockIdx.x * 4;
    const int bt = b0 >> 7;
    const int r = b0 & 127;
    const int swm = r >> 6, srt = (r >> 4) & 3, squad = (r >> 2) & 3;

    // stage: 16 iters x 512 threads = 8192 (v,o) pairs, 8 B each
#pragma unroll
    for (int c = 0; c < 16; ++c) {
        const int p = c * 512 + t;
        const int v = p >> 7, o = p & 127;
        const size_t off = (size_t)(bt * 64 + v) * 16384
                         + (size_t)(((swm * 2 + (o >> 6)) * 4 + ((o >> 4) & 3)) * 4 + srt) * 256
                         + (size_t)(squad * 16 + (o & 15)) * 4;
        const uint2 pk = *(const uint2*)(h + off);
        const float sc = scale[v * DO + o];
        hsT[0][o][v] = f2bf(bf2f((unsigned short)(pk.x & 0xFFFF)) * sc);
        hsT[1][o][v] = f2bf(bf2f((unsigned short)(pk.x >> 16)) * sc);
        hsT[2][o][v] = f2bf(bf2f((unsigned short)(pk.y & 0xFFFF)) * sc);
        hsT[3][o][v] = f2bf(bf2f((unsigned short)(pk.y >> 16)) * sc);
    }
    __syncthreads();

    const int w = t >> 6, lane = t & 63;
    const int bl = w >> 1, nh = w & 1;
    const int quad = lane >> 4, l16 = lane & 15;
    const int b = b0 + bl;

    short8 af[4][2];
#pragma unroll
    for (int mt = 0; mt < 4; ++mt)
#pragma unroll
        for (int ks = 0; ks < 2; ++ks)
            af[mt][ks] = *(const short8*)(adjbf + (mt * 16 + l16) * VN
                                          + ks * 32 + quad * 8);

    f32x4 acc[4][4];
#pragma unroll
    for (int mt = 0; mt < 4; ++mt)
#pragma unroll
        for (int nt = 0; nt < 4; ++nt) acc[mt][nt] = (f32x4){0.f, 0.f, 0.f, 0.f};

#pragma unroll
    for (int nt = 0; nt < 4; ++nt) {
        const unsigned short* bp = &hsT[bl][nh * 64 + nt * 16 + l16][quad * 8];
        short8 bf0 = *(const short8*)(bp);
        short8 bf1 = *(const short8*)(bp + 32);
#pragma unroll
        for (int mt = 0; mt < 4; ++mt) {
            acc[mt][nt] = __builtin_amdgcn_mfma_f32_16x16x32_bf16(
                af[mt][0], bf0, acc[mt][nt], 0, 0, 0);
            acc[mt][nt] = __builtin_amdgcn_mfma_f32_16x16x32_bf16(
                af[mt][1], bf1, acc[mt][nt], 0, 0, 0);
        }
    }

#pragma unroll
    for (int mt = 0; mt < 4; ++mt)
#pragma unroll
        for (int nt = 0; nt < 4; ++nt) {
            const int o = nh * 64 + nt * 16 + l16;
#pragma unroll
            for (int e = 0; e < 4; ++e) {
                const int u = mt * 16 + quad * 4 + e;
                out[((size_t)b * VN + u) * DO + o] =
                    fmaxf(acc[mt][nt][e] + C0[u * DO + o], 0.0f);
            }
        }
}

// ---------------------------------------------------------------------------
extern "C" void kernel_launch(void* const* d_in, const int* in_sizes, int n_in,
                              void* d_out, int out_size, void* d_ws, size_t ws_size,
                              hipStream_t stream) {
    const float* feat  = (const float*)d_in[0];
    const float* adj   = (const float*)d_in[1];
    const float* W     = (const float*)d_in[2];
    const float* bias  = (const float*)d_in[3];
    const float* gamma = (const float*)d_in[4];
    const float* beta  = (const float*)d_in[5];
    float* out = (float*)d_out;

    char* ws = (char*)d_ws;
    unsigned short* h     = (unsigned short*)ws;                 // 67,108,864 B
    unsigned short* Wt    = (unsigned short*)(ws + 67108864ull); //  2,097,152 B
    unsigned short* adjbf = (unsigned short*)(ws + 69206016ull); //      8,192 B
    float* psA   = (float*)(ws + 69214208ull);                   //  2 MiB
    float* psB   = psA + 524288;                                 //  2 MiB
    float* scale = psB + 524288;                                 // 32 KiB
    float* shift = scale + 8192;                                 // 32 KiB
    float* C0    = shift + 8192;                                 // 32 KiB

    k_prep<<<dim3(513), dim3(256), 0, stream>>>(W, adj, Wt, adjbf);
    k_gemm1<<<dim3(64, 32), dim3(256), 0, stream>>>(feat, Wt, bias, h, psA, psB);
    k_reduce<<<dim3(64), dim3(128), 0, stream>>>(psA, psB, gamma, beta, scale, shift);
    k_c0<<<dim3(64), dim3(128), 0, stream>>>(adj, shift, C0);
    k_mix<<<dim3(1024), dim3(512), 0, stream>>>(h, scale, adjbf, C0, out);
}